// Round 9
// baseline (141.264 us; speedup 1.0000x reference)
//
#include <hip/hip_runtime.h>
#include <hip/hip_bf16.h>
#include <stdint.h>
#include <math.h>

#define SEQ 4096
#define DIM 1024

typedef __attribute__((ext_vector_type(8))) __bf16 bf16x8;
typedef __attribute__((ext_vector_type(4))) float f32x4;
typedef __attribute__((ext_vector_type(8))) unsigned short u16x8;

__device__ __forceinline__ unsigned short f2bf(float f) {
  unsigned int u = __float_as_uint(f);
  u = (u + 0x7FFFu + ((u >> 16) & 1u)) >> 16;
  return (unsigned short)u;
}

// swz for 128B-row tiles ([.][64] bf16): spread 8 16B slots by row&7 — conflict-free (R2-R7)
__device__ __forceinline__ int swz(int o) { return o ^ (((o >> 7) & 7) << 4); }

template <int N> __device__ __forceinline__ void wait_vm() {
  if constexpr (N == 0) asm volatile("s_waitcnt vmcnt(0)" ::: "memory");
  else if constexpr (N == 6) asm volatile("s_waitcnt vmcnt(6)" ::: "memory");
  else if constexpr (N == 8) asm volatile("s_waitcnt vmcnt(8)" ::: "memory");
}

// ---------------- fused f32 -> bf16 convert: x, Wq, Wk, Wv ----------------
__global__ void __launch_bounds__(256) cvt_all(const float* __restrict__ x,
                                               const float* __restrict__ wq,
                                               const float* __restrict__ wk,
                                               const float* __restrict__ wv,
                                               unsigned short* __restrict__ xb,
                                               unsigned short* __restrict__ wqk,
                                               unsigned short* __restrict__ wvb) {
  const int bid = blockIdx.x;
  const float* src;
  unsigned short* dst;
  size_t base;
  if (bid < 2048)      { src = x;  dst = xb;                base = (size_t)bid * 2048; }
  else if (bid < 2560) { src = wq; dst = wqk;               base = (size_t)(bid - 2048) * 2048; }
  else if (bid < 3072) { src = wk; dst = wqk + 1024 * 1024; base = (size_t)(bid - 2560) * 2048; }
  else                 { src = wv; dst = wvb;               base = (size_t)(bid - 3072) * 2048; }
  size_t i = base + (size_t)threadIdx.x * 8;
  float4 a = *reinterpret_cast<const float4*>(src + i);
  float4 b = *reinterpret_cast<const float4*>(src + i + 4);
  u16x8 o;
  o[0] = f2bf(a.x); o[1] = f2bf(a.y); o[2] = f2bf(a.z); o[3] = f2bf(a.w);
  o[4] = f2bf(b.x); o[5] = f2bf(b.y); o[6] = f2bf(b.z); o[7] = f2bf(b.w);
  *reinterpret_cast<u16x8*>(dst + i) = o;
}

// ============ PROVEN 128x128 GEMM body: BK=64, 4 waves, 64KB LDS ============
// (R5/R7 proj structure, ~860 TF measured in-pipeline; conflicts = 0)
__device__ __forceinline__ void gemm128_64(const unsigned short* __restrict__ A,
                                           const unsigned short* __restrict__ B,
                                           unsigned short* __restrict__ C,
                                           unsigned short* As, unsigned short* Bs,
                                           int lda, int ldb, int ldc,
                                           int tr, int tc, float scale) {
  constexpr int NT = 16;  // K = 1024 = 16 x 64
  const int tid = threadIdx.x;
  const int lane = tid & 63;
  const int wid = tid >> 6;
  const int wr = wid >> 1, wc = wid & 1;
  const int l15 = lane & 15;
  const int kq = lane >> 4;

  f32x4 acc[4][4];
  #pragma unroll
  for (int m = 0; m < 4; ++m)
    #pragma unroll
    for (int n = 0; n < 4; ++n)
      acc[m][n] = (f32x4){0.f, 0.f, 0.f, 0.f};

  const unsigned short* Abase = A + (size_t)tr * 128 * lda;
  const unsigned short* Bbase = B + (size_t)tc * 128 * ldb;

  auto stage = [&](int buf, int kt) {
    const int k0 = kt << 6;
    #pragma unroll
    for (int i = 0; i < 4; ++i) {
      const int o = (i * 256 + tid) * 16;
      const int cs = (swz(o) >> 4) & 7;
      const unsigned short* ga = Abase + (size_t)(o >> 7) * lda + k0 + cs * 8;
      const unsigned short* gb = Bbase + (size_t)(o >> 7) * ldb + k0 + cs * 8;
      __builtin_amdgcn_global_load_lds(
          (const __attribute__((address_space(1))) unsigned int*)ga,
          (__attribute__((address_space(3))) unsigned int*)((char*)(As + buf * 8192) + o), 16, 0, 0);
      __builtin_amdgcn_global_load_lds(
          (const __attribute__((address_space(1))) unsigned int*)gb,
          (__attribute__((address_space(3))) unsigned int*)((char*)(Bs + buf * 8192) + o), 16, 0, 0);
    }
  };

  stage(0, 0);
  int cur = 0;
  for (int kt = 0; kt < NT; ++kt) {
    if (kt + 1 < NT) { stage(cur ^ 1, kt + 1); wait_vm<8>(); }
    else wait_vm<0>();
    __builtin_amdgcn_s_barrier();

    bf16x8 af[4][2], bv[4][2];
    #pragma unroll
    for (int m = 0; m < 4; ++m)
      #pragma unroll
      for (int ks = 0; ks < 2; ++ks) {
        const int row = wr * 64 + m * 16 + l15;
        af[m][ks] = *reinterpret_cast<const bf16x8*>(
            (const char*)(As + cur * 8192) + swz(row * 128 + kq * 16 + ks * 64));
      }
    #pragma unroll
    for (int n = 0; n < 4; ++n)
      #pragma unroll
      for (int ks = 0; ks < 2; ++ks) {
        const int row = wc * 64 + n * 16 + l15;
        bv[n][ks] = *reinterpret_cast<const bf16x8*>(
            (const char*)(Bs + cur * 8192) + swz(row * 128 + kq * 16 + ks * 64));
      }
    __builtin_amdgcn_s_setprio(1);
    #pragma unroll
    for (int m = 0; m < 4; ++m)
      #pragma unroll
      for (int n = 0; n < 4; ++n) {
        acc[m][n] = __builtin_amdgcn_mfma_f32_16x16x32_bf16(af[m][0], bv[n][0], acc[m][n], 0, 0, 0);
        acc[m][n] = __builtin_amdgcn_mfma_f32_16x16x32_bf16(af[m][1], bv[n][1], acc[m][n], 0, 0, 0);
      }
    __builtin_amdgcn_s_setprio(0);
    __builtin_amdgcn_s_barrier();
    cur ^= 1;
  }

  const int rbase = tr * 128 + wr * 64 + kq * 4;
  const int cbase = tc * 128 + wc * 64 + l15;
  #pragma unroll
  for (int m = 0; m < 4; ++m)
    #pragma unroll
    for (int n = 0; n < 4; ++n)
      #pragma unroll
      for (int i = 0; i < 4; ++i)
        C[(size_t)(rbase + m * 16 + i) * ldc + cbase + n * 16] = f2bf(acc[m][n][i] * scale);
}

// ---------------- D1: Q|K projection (512) + V^T (256) = 768 blocks, 3/CU ----
__global__ void __launch_bounds__(256) projvt_kernel(const unsigned short* __restrict__ xb,
                                                     const unsigned short* __restrict__ wqk,
                                                     const unsigned short* __restrict__ wvb,
                                                     unsigned short* __restrict__ qkb,
                                                     unsigned short* __restrict__ vt) {
  __shared__ __align__(16) unsigned short As[2 * 128 * 64];
  __shared__ __align__(16) unsigned short Bs[2 * 128 * 64];
  // chunked XCD swizzle (768 = 8 x 96): contiguous tile-chunks per XCD
  const int bid = (blockIdx.x & 7) * 96 + (blockIdx.x >> 3);
  if (bid < 512) {
    gemm128_64(xb, wqk, qkb, As, Bs, DIM, DIM, 2048, bid >> 4, bid & 15, 1.0f);
  } else {
    const int t = bid - 512;
    gemm128_64(wvb, xb, vt, As, Bs, DIM, DIM, SEQ, t >> 5, t & 31, 1.0f);
  }
}

// ---------------- D2: causal QK^T, 528 uniform 128x128 tiles (~2/CU) ----------
__global__ void __launch_bounds__(256) qkt_kernel(const unsigned short* __restrict__ qkb,
                                                  unsigned short* __restrict__ S) {
  __shared__ __align__(16) unsigned short As[2 * 128 * 64];
  __shared__ __align__(16) unsigned short Bs[2 * 128 * 64];
  // chunked XCD swizzle (528 = 8 x 66)
  const int b = (blockIdx.x & 7) * 66 + (blockIdx.x >> 3);
  int tr = (int)((sqrtf(8.0f * b + 1.0f) - 1.0f) * 0.5f);
  while ((tr + 1) * (tr + 2) / 2 <= b) ++tr;
  while (tr * (tr + 1) / 2 > b) --tr;
  const int tc = b - tr * (tr + 1) / 2;
  gemm128_64(qkb, qkb + 1024, S, As, Bs, 2048, 2048, SEQ, tr, tc, 0.03125f);
}

// ---------------- PV GEMM (split-K, proven R5-R8) ----------------
__global__ void __launch_bounds__(256) pv_kernel(const unsigned short* __restrict__ A,
                                                 const unsigned short* __restrict__ B,
                                                 float* __restrict__ C,
                                                 float* __restrict__ P1, float* __restrict__ P2,
                                                 float* __restrict__ P3) {
  constexpr int BM = 64;
  constexpr int lda = SEQ, ldb = SEQ, ldc = DIM;
  int tc = blockIdx.x, tr = blockIdx.y;
  const int s = blockIdx.z;
  const int ltiles = tr + 1;
  int kt0 = s * 16;
  if (kt0 >= ltiles) return;
  const int nt = min(ltiles, kt0 + 16) - kt0;

  __shared__ __align__(16) unsigned short As[2][BM * 64];
  __shared__ __align__(16) unsigned short Bs[2][128 * 64];

  const int tid = threadIdx.x;
  const int lane = tid & 63;
  const int wid = tid >> 6;
  const int wr = wid >> 1, wc = wid & 1;
  const int l15 = lane & 15;
  const int kq = lane >> 4;

  f32x4 acc[2][4];
  #pragma unroll
  for (int m = 0; m < 2; ++m)
    #pragma unroll
    for (int n = 0; n < 4; ++n)
      acc[m][n] = (f32x4){0.f, 0.f, 0.f, 0.f};

  const unsigned short* Abase = A + (size_t)tr * BM * lda;
  const unsigned short* Bbase = B + (size_t)tc * 128 * ldb;

  auto stage = [&](int buf, int ktabs) {
    const int k0 = ktabs << 6;
    #pragma unroll
    for (int i = 0; i < 2; ++i) {
      const int o = (i * 256 + tid) * 16;
      const int cs = (swz(o) >> 4) & 7;
      const unsigned short* g = Abase + (size_t)(o >> 7) * lda + k0 + cs * 8;
      __builtin_amdgcn_global_load_lds(
          (const __attribute__((address_space(1))) unsigned int*)g,
          (__attribute__((address_space(3))) unsigned int*)((char*)&As[buf][0] + o), 16, 0, 0);
    }
    #pragma unroll
    for (int i = 0; i < 4; ++i) {
      const int o = (i * 256 + tid) * 16;
      const int cs = (swz(o) >> 4) & 7;
      const unsigned short* g = Bbase + (size_t)(o >> 7) * ldb + k0 + cs * 8;
      __builtin_amdgcn_global_load_lds(
          (const __attribute__((address_space(1))) unsigned int*)g,
          (__attribute__((address_space(3))) unsigned int*)((char*)&Bs[buf][0] + o), 16, 0, 0);
    }
  };

  stage(0, kt0);
  int cur = 0;
  for (int kt = 0; kt < nt; ++kt) {
    if (kt + 1 < nt) { stage(cur ^ 1, kt0 + kt + 1); wait_vm<6>(); }
    else wait_vm<0>();
    __builtin_amdgcn_s_barrier();

    bf16x8 af[2][2], bv[4][2];
    #pragma unroll
    for (int m = 0; m < 2; ++m)
      #pragma unroll
      for (int ks = 0; ks < 2; ++ks) {
        const int row = wr * 32 + m * 16 + l15;
        af[m][ks] = *reinterpret_cast<const bf16x8*>(
            (const char*)&As[cur][0] + swz(row * 128 + kq * 16 + ks * 64));
      }
    #pragma unroll
    for (int n = 0; n < 4; ++n)
      #pragma unroll
      for (int ks = 0; ks < 2; ++ks) {
        const int row = wc * 64 + n * 16 + l15;
        bv[n][ks] = *reinterpret_cast<const bf16x8*>(
            (const char*)&Bs[cur][0] + swz(row * 128 + kq * 16 + ks * 64));
      }
    #pragma unroll
    for (int m = 0; m < 2; ++m)
      #pragma unroll
      for (int n = 0; n < 4; ++n) {
        acc[m][n] = __builtin_amdgcn_mfma_f32_16x16x32_bf16(af[m][0], bv[n][0], acc[m][n], 0, 0, 0);
        acc[m][n] = __builtin_amdgcn_mfma_f32_16x16x32_bf16(af[m][1], bv[n][1], acc[m][n], 0, 0, 0);
      }
    __builtin_amdgcn_s_barrier();
    cur ^= 1;
  }

  float* fdst = C;
  int rowoff = 0;
  if (s == 1) { fdst = P1; rowoff = 1024; }
  else if (s == 2) { fdst = P2; rowoff = 2048; }
  else if (s == 3) { fdst = P3; rowoff = 3072; }
  const int rbase = tr * BM + wr * 32 + kq * 4;
  const int cbase = tc * 128 + wc * 64 + l15;
  #pragma unroll
  for (int m = 0; m < 2; ++m)
    #pragma unroll
    for (int n = 0; n < 4; ++n)
      #pragma unroll
      for (int i = 0; i < 4; ++i)
        fdst[(size_t)(rbase + m * 16 + i - rowoff) * ldc + cbase + n * 16] = acc[m][n][i];
}

// ---------------- split-K reduction ----------------
__global__ void __launch_bounds__(256) reduce_kernel(float* __restrict__ out,
                                                     const float* __restrict__ p1,
                                                     const float* __restrict__ p2,
                                                     const float* __restrict__ p3) {
  const int b = blockIdx.x;
  const size_t e = ((size_t)b * 1024) + threadIdx.x * 4;
  f32x4 acc = *reinterpret_cast<f32x4*>(out + (size_t)1024 * 1024 + e);
  acc += *reinterpret_cast<const f32x4*>(p1 + e);
  if (b >= 1024) acc += *reinterpret_cast<const f32x4*>(p2 + e - (size_t)1024 * 1024);
  if (b >= 2048) acc += *reinterpret_cast<const f32x4*>(p3 + e - (size_t)2048 * 1024);
  *reinterpret_cast<f32x4*>(out + (size_t)1024 * 1024 + e) = acc;
}

// ---------------- in-place causal row softmax ----------------
__global__ void __launch_bounds__(256) softmax_causal(unsigned short* __restrict__ S) {
  const int row = blockIdx.x;
  const int limit = ((row >> 6) + 1) << 6;
  unsigned short* Srow = S + (size_t)row * SEQ;
  const int tid = threadIdx.x;
  const int lane = tid & 63, wid = tid >> 6;

  float vals[16];
  bool act[2];
  #pragma unroll
  for (int i = 0; i < 2; ++i) {
    const int j0 = (tid + i * 256) * 8;
    act[i] = j0 < limit;
    if (act[i]) {
      const uint4 w = *reinterpret_cast<const uint4*>(Srow + j0);
      const unsigned int wb[4] = {w.x, w.y, w.z, w.w};
      #pragma unroll
      for (int e = 0; e < 4; ++e) {
        vals[i * 8 + 2 * e]     = __uint_as_float(wb[e] << 16);
        vals[i * 8 + 2 * e + 1] = __uint_as_float(wb[e] & 0xFFFF0000u);
      }
    } else {
      #pragma unroll
      for (int e = 0; e < 8; ++e) vals[i * 8 + e] = -1e30f;
    }
  }

  float m = -1e30f;
  #pragma unroll
  for (int i = 0; i < 2; ++i)
    #pragma unroll
    for (int e = 0; e < 8; ++e) {
      int j = (tid + i * 256) * 8 + e;
      if (j <= row) m = fmaxf(m, vals[i * 8 + e]);
    }
  #pragma unroll
  for (int off = 32; off > 0; off >>= 1) m = fmaxf(m, __shfl_xor(m, off));
  __shared__ float redm[4], reds[4];
  if (lane == 0) redm[wid] = m;
  __syncthreads();
  m = fmaxf(fmaxf(redm[0], redm[1]), fmaxf(redm[2], redm[3]));

  float s = 0.f;
  float ev[16];
  #pragma unroll
  for (int i = 0; i < 2; ++i)
    #pragma unroll
    for (int e = 0; e < 8; ++e) {
      int j = (tid + i * 256) * 8 + e;
      float ex = (j <= row) ? __expf(vals[i * 8 + e] - m) : 0.f;
      ev[i * 8 + e] = ex;
      s += ex;
    }
  #pragma unroll
  for (int off = 32; off > 0; off >>= 1) s += __shfl_xor(s, off);
  if (lane == 0) reds[wid] = s;
  __syncthreads();
  s = reds[0] + reds[1] + reds[2] + reds[3];
  const float inv = 1.f / s;

  #pragma unroll
  for (int i = 0; i < 2; ++i) {
    if (!act[i]) continue;
    u16x8 o;
    #pragma unroll
    for (int e = 0; e < 8; ++e) o[e] = f2bf(ev[i * 8 + e] * inv);
    *reinterpret_cast<u16x8*>(Srow + (tid + i * 256) * 8) = o;
  }
}

extern "C" void kernel_launch(void* const* d_in, const int* in_sizes, int n_in,
                              void* d_out, int out_size, void* d_ws, size_t ws_size,
                              hipStream_t stream) {
  const float* x  = (const float*)d_in[0];
  const float* Wq = (const float*)d_in[1];
  const float* Wk = (const float*)d_in[2];
  const float* Wv = (const float*)d_in[3];
  float* out = (float*)d_out;

  char* ws = (char*)d_ws;
  const size_t MB = 1u << 20;
  unsigned short* xb   = (unsigned short*)(ws + 0 * MB);   // 8 MB  (dead after D1)
  unsigned short* wqk  = (unsigned short*)(ws + 8 * MB);   // 4 MB
  unsigned short* wvb  = (unsigned short*)(ws + 12 * MB);  // 2 MB
  unsigned short* qkb  = (unsigned short*)(ws + 14 * MB);  // 16 MB Q|K [4096][2048]
  unsigned short* vt   = (unsigned short*)(ws + 30 * MB);  // 8 MB  V^T [1024][4096]
  unsigned short* S    = (unsigned short*)(ws + 38 * MB);  // 32 MB (-> P in place)
  float* p1 = (float*)(ws + 0 * MB);    // 12 MB (reuse after D1/D2)
  float* p2 = (float*)(ws + 12 * MB);   // 8 MB
  float* p3 = (float*)(ws + 20 * MB);   // 4 MB

  cvt_all<<<3584, 256, 0, stream>>>(x, Wq, Wk, Wv, xb, wqk, wvb);

  // D1: Q|K projection (512) + V^T (256) — 768 blocks, uniform 3/CU, BK=64 body
  projvt_kernel<<<768, 256, 0, stream>>>(xb, wqk, wvb, qkb, vt);

  // D2: causal QK^T — 528 uniform 128² tiles, BK=64 body
  qkt_kernel<<<528, 256, 0, stream>>>(qkb, S);

  softmax_causal<<<SEQ, 256, 0, stream>>>(S);

  pv_kernel<<<dim3(DIM / 128, SEQ / 64, 4), 256, 0, stream>>>(S, vt, out, p1, p2, p3);
  reduce_kernel<<<3072, 256, 0, stream>>>(out, p1, p2, p3);
}

// Round 10
// 123.154 us; speedup vs baseline: 1.1471x; 1.1471x over previous
//
#include <hip/hip_runtime.h>
#include <hip/hip_bf16.h>
#include <stdint.h>
#include <math.h>

#define SEQ 4096
#define DIM 1024

typedef __attribute__((ext_vector_type(8))) __bf16 bf16x8;
typedef __attribute__((ext_vector_type(4))) float f32x4;
typedef __attribute__((ext_vector_type(8))) unsigned short u16x8;

__device__ __forceinline__ unsigned short f2bf(float f) {
  unsigned int u = __float_as_uint(f);
  u = (u + 0x7FFFu + ((u >> 16) & 1u)) >> 16;
  return (unsigned short)u;
}

// XOR swizzle: spreads the 8 16B-slots of each 128B LDS row across banks.
__device__ __forceinline__ int swz(int o) { return o ^ (((o >> 7) & 7) << 4); }

template <int N> __device__ __forceinline__ void wait_vm() {
  if constexpr (N == 0) asm volatile("s_waitcnt vmcnt(0)" ::: "memory");
  else if constexpr (N == 4) asm volatile("s_waitcnt vmcnt(4)" ::: "memory");
  else if constexpr (N == 6) asm volatile("s_waitcnt vmcnt(6)" ::: "memory");
  else if constexpr (N == 8) asm volatile("s_waitcnt vmcnt(8)" ::: "memory");
}

// ---------------- fused f32 -> bf16 convert: x, Wq, Wk, Wv ----------------
__global__ void __launch_bounds__(256) cvt_all(const float* __restrict__ x,
                                               const float* __restrict__ wq,
                                               const float* __restrict__ wk,
                                               const float* __restrict__ wv,
                                               unsigned short* __restrict__ xb,
                                               unsigned short* __restrict__ wqk,
                                               unsigned short* __restrict__ wvb) {
  const int bid = blockIdx.x;
  const float* src;
  unsigned short* dst;
  size_t base;
  if (bid < 2048)      { src = x;  dst = xb;                base = (size_t)bid * 2048; }
  else if (bid < 2560) { src = wq; dst = wqk;               base = (size_t)(bid - 2048) * 2048; }
  else if (bid < 3072) { src = wk; dst = wqk + 1024 * 1024; base = (size_t)(bid - 2560) * 2048; }
  else                 { src = wv; dst = wvb;               base = (size_t)(bid - 3072) * 2048; }
  size_t i = base + (size_t)threadIdx.x * 8;
  float4 a = *reinterpret_cast<const float4*>(src + i);
  float4 b = *reinterpret_cast<const float4*>(src + i + 4);
  u16x8 o;
  o[0] = f2bf(a.x); o[1] = f2bf(a.y); o[2] = f2bf(a.z); o[3] = f2bf(a.w);
  o[4] = f2bf(b.x); o[5] = f2bf(b.y); o[6] = f2bf(b.z); o[7] = f2bf(b.w);
  *reinterpret_cast<u16x8*>(dst + i) = o;
}

// ---------------- 128x128 2-phase GEMM, 4 waves (R7 proven, no setprio) ----
__global__ void __launch_bounds__(256) proj_qk(const unsigned short* __restrict__ A,
                                               const unsigned short* __restrict__ B,
                                               unsigned short* __restrict__ C) {
  constexpr int lda = DIM, ldb = DIM, ldc = 2048;
  const int tr = blockIdx.x >> 4, tc = blockIdx.x & 15;

  __shared__ __align__(16) unsigned short As[2][128 * 64];
  __shared__ __align__(16) unsigned short Bs[2][128 * 64];

  const int tid = threadIdx.x;
  const int lane = tid & 63;
  const int wid = tid >> 6;
  const int wr = wid >> 1, wc = wid & 1;
  const int l15 = lane & 15;
  const int kq = lane >> 4;

  f32x4 acc[4][4];
  #pragma unroll
  for (int m = 0; m < 4; ++m)
    #pragma unroll
    for (int n = 0; n < 4; ++n)
      acc[m][n] = (f32x4){0.f, 0.f, 0.f, 0.f};

  const unsigned short* Abase = A + (size_t)tr * 128 * lda;
  const unsigned short* Bbase = B + (size_t)tc * 128 * ldb;

  auto stage = [&](int buf, int kt) {
    const int k0 = kt << 6;
    #pragma unroll
    for (int i = 0; i < 4; ++i) {
      const int o = (i * 256 + tid) * 16;
      const int cs = (swz(o) >> 4) & 7;
      const unsigned short* ga = Abase + (size_t)(o >> 7) * lda + k0 + cs * 8;
      const unsigned short* gb = Bbase + (size_t)(o >> 7) * ldb + k0 + cs * 8;
      __builtin_amdgcn_global_load_lds(
          (const __attribute__((address_space(1))) unsigned int*)ga,
          (__attribute__((address_space(3))) unsigned int*)((char*)&As[buf][0] + o), 16, 0, 0);
      __builtin_amdgcn_global_load_lds(
          (const __attribute__((address_space(1))) unsigned int*)gb,
          (__attribute__((address_space(3))) unsigned int*)((char*)&Bs[buf][0] + o), 16, 0, 0);
    }
  };

  stage(0, 0);
  int cur = 0;
  for (int kt = 0; kt < 16; ++kt) {
    if (kt + 1 < 16) { stage(cur ^ 1, kt + 1); wait_vm<8>(); }
    else wait_vm<0>();
    __builtin_amdgcn_s_barrier();

    bf16x8 af[4][2], bv[4][2];
    #pragma unroll
    for (int m = 0; m < 4; ++m)
      #pragma unroll
      for (int ks = 0; ks < 2; ++ks) {
        const int row = wr * 64 + m * 16 + l15;
        af[m][ks] = *reinterpret_cast<const bf16x8*>(
            (const char*)&As[cur][0] + swz(row * 128 + kq * 16 + ks * 64));
      }
    #pragma unroll
    for (int n = 0; n < 4; ++n)
      #pragma unroll
      for (int ks = 0; ks < 2; ++ks) {
        const int row = wc * 64 + n * 16 + l15;
        bv[n][ks] = *reinterpret_cast<const bf16x8*>(
            (const char*)&Bs[cur][0] + swz(row * 128 + kq * 16 + ks * 64));
      }
    #pragma unroll
    for (int m = 0; m < 4; ++m)
      #pragma unroll
      for (int n = 0; n < 4; ++n) {
        acc[m][n] = __builtin_amdgcn_mfma_f32_16x16x32_bf16(af[m][0], bv[n][0], acc[m][n], 0, 0, 0);
        acc[m][n] = __builtin_amdgcn_mfma_f32_16x16x32_bf16(af[m][1], bv[n][1], acc[m][n], 0, 0, 0);
      }
    __builtin_amdgcn_s_barrier();
    cur ^= 1;
  }

  const int rbase = tr * 128 + wr * 64 + kq * 4;
  const int cbase = tc * 128 + wc * 64 + l15;
  #pragma unroll
  for (int m = 0; m < 4; ++m)
    #pragma unroll
    for (int n = 0; n < 4; ++n)
      #pragma unroll
      for (int i = 0; i < 4; ++i)
        C[(size_t)(rbase + m * 16 + i) * ldc + cbase + n * 16] = f2bf(acc[m][n][i]);
}

// ============ fused dispatch: causal QK^T (bid<136, R5 16x16 body) + V^T ====
__global__ void __launch_bounds__(512) qkt_vt(const unsigned short* __restrict__ Q,
                                              const unsigned short* __restrict__ K,
                                              unsigned short* __restrict__ S,
                                              const unsigned short* __restrict__ wvb,
                                              const unsigned short* __restrict__ xb,
                                              unsigned short* __restrict__ vt) {
  __shared__ __align__(16) unsigned short As[2][256 * 64];
  __shared__ __align__(16) unsigned short Bs[2][256 * 64];

  const int bid = blockIdx.x;
  const int tid = threadIdx.x;
  const int lane = tid & 63;
  const int wid = tid >> 6;

  if (bid < 136) {
    // ---------------- causal QK^T: R5-verified 256², 16x16x32, 8-phase ------
    int tr = (int)((sqrtf(8.0f * bid + 1.0f) - 1.0f) * 0.5f);
    while ((tr + 1) * (tr + 2) / 2 <= bid) ++tr;
    while (tr * (tr + 1) / 2 > bid) --tr;
    const int tc = bid - tr * (tr + 1) / 2;

    constexpr int LDA = 2 * DIM, LDC = SEQ;
    constexpr float SCALE = 0.03125f;
    const int wr = wid >> 2;   // 0..1
    const int wc = wid & 3;    // 0..3
    const int l15 = lane & 15;
    const int kq = lane >> 4;

    const unsigned short* Abase = Q + (size_t)tr * 256 * LDA;
    const unsigned short* Bbase = K + (size_t)tc * 256 * LDA;

    f32x4 acc[8][4];
    #pragma unroll
    for (int m = 0; m < 8; ++m)
      #pragma unroll
      for (int n = 0; n < 4; ++n)
        acc[m][n] = (f32x4){0.f, 0.f, 0.f, 0.f};

    // h: 0=B rows0-127, 1=B rows128-255, 2=A rows0-127, 3=A rows128-255
    auto stage_half = [&](int buf, int kt, int h) {
      const int k0 = kt << 6;
      const bool isB = (h < 2);
      unsigned short* lb = isB ? &Bs[buf][0] : &As[buf][0];
      const unsigned short* gb = isB ? Bbase : Abase;
      #pragma unroll
      for (int i = 0; i < 2; ++i) {
        const int ot = ((h & 1) << 14) + ((i * 512 + tid) << 4);
        const int row = ot >> 7;
        const int cs = (swz(ot) >> 4) & 7;
        const unsigned short* g = gb + (size_t)row * LDA + k0 + cs * 8;
        __builtin_amdgcn_global_load_lds(
            (const __attribute__((address_space(1))) unsigned int*)g,
            (__attribute__((address_space(3))) unsigned int*)((char*)lb + ot), 16, 0, 0);
      }
    };

    bf16x8 a[4][2], bn0[2][2], bn1[2][2];

    auto rdA = [&](int b, int mi) {
      #pragma unroll
      for (int f = 0; f < 4; ++f) {
        const int row = wr * 128 + mi * 64 + f * 16 + l15;
        #pragma unroll
        for (int ks = 0; ks < 2; ++ks)
          a[f][ks] = *reinterpret_cast<const bf16x8*>(
              (const char*)&As[b][0] + swz(row * 128 + kq * 16 + ks * 64));
      }
    };
    auto rdB = [&](bf16x8 (&dst)[2][2], int b, int n) {
      #pragma unroll
      for (int g = 0; g < 2; ++g) {
        const int row = wc * 64 + n * 32 + g * 16 + l15;
        #pragma unroll
        for (int ks = 0; ks < 2; ++ks)
          dst[g][ks] = *reinterpret_cast<const bf16x8*>(
              (const char*)&Bs[b][0] + swz(row * 128 + kq * 16 + ks * 64));
      }
    };
    auto mma = [&](int mi, int n, bf16x8 (&bb)[2][2]) {
      #pragma unroll
      for (int f = 0; f < 4; ++f)
        #pragma unroll
        for (int g = 0; g < 2; ++g) {
          acc[mi * 4 + f][n * 2 + g] =
              __builtin_amdgcn_mfma_f32_16x16x32_bf16(a[f][0], bb[g][0], acc[mi * 4 + f][n * 2 + g], 0, 0, 0);
          acc[mi * 4 + f][n * 2 + g] =
              __builtin_amdgcn_mfma_f32_16x16x32_bf16(a[f][1], bb[g][1], acc[mi * 4 + f][n * 2 + g], 0, 0, 0);
        }
    };

    // Prologue: tile0 fully + tile1 B halves (steady-state order)
    stage_half(0, 0, 0); stage_half(0, 0, 1); stage_half(0, 0, 2); stage_half(0, 0, 3);
    stage_half(1, 1, 0); stage_half(1, 1, 1);
    wait_vm<4>();
    __builtin_amdgcn_s_barrier();

    #pragma unroll 1
    for (int kt = 0; kt < 16; ++kt) {
      const int b = kt & 1;
      const bool pf1 = (kt + 1 < 16);
      const bool pf2 = (kt + 2 < 16);
      // ph0: (mi0, n0)
      rdA(b, 0);
      rdB(bn0, b, 0);
      if (pf1) stage_half(b ^ 1, kt + 1, 2);
      __builtin_amdgcn_s_barrier();
      __builtin_amdgcn_s_setprio(1); mma(0, 0, bn0); __builtin_amdgcn_s_setprio(0);
      __builtin_amdgcn_s_barrier();
      // ph1: (mi0, n1)
      rdB(bn1, b, 1);
      if (pf1) stage_half(b ^ 1, kt + 1, 3);
      __builtin_amdgcn_s_barrier();
      __builtin_amdgcn_s_setprio(1); mma(0, 1, bn1); __builtin_amdgcn_s_setprio(0);
      __builtin_amdgcn_s_barrier();
      // ph2: (mi1, n1)
      rdA(b, 1);
      if (pf2) stage_half(b, kt + 2, 0);
      __builtin_amdgcn_s_barrier();
      __builtin_amdgcn_s_setprio(1); mma(1, 1, bn1); __builtin_amdgcn_s_setprio(0);
      __builtin_amdgcn_s_barrier();
      // ph3: (mi1, n0)
      if (pf2) stage_half(b, kt + 2, 1);
      if (pf1) { if (pf2) wait_vm<4>(); else wait_vm<0>(); }
      __builtin_amdgcn_s_barrier();
      __builtin_amdgcn_s_setprio(1); mma(1, 0, bn0); __builtin_amdgcn_s_setprio(0);
      __builtin_amdgcn_s_barrier();
    }

    const int rb = tr * 256 + wr * 128 + kq * 4;
    const int cb = tc * 256 + wc * 64 + l15;
    #pragma unroll
    for (int am = 0; am < 8; ++am)
      #pragma unroll
      for (int an = 0; an < 4; ++an)
        #pragma unroll
        for (int i = 0; i < 4; ++i)
          S[(size_t)(rb + am * 16 + i) * LDC + cb + an * 16] = f2bf(acc[am][an][i] * SCALE);
    return;
  }

  // ---------------- V^T = Wv x^T : 128x128 tiles, 8 waves (R7 proven) -------
  const int wr = wid >> 1;   // 0..3
  const int wc = wid & 1;    // 0..1
  const int l15 = lane & 15;
  const int kq = lane >> 4;
  unsigned short* A0 = &As[0][0];
  unsigned short* B0 = &Bs[0][0];

  for (int t = bid - 136; t < 256; t += 120) {
    const int tr = t >> 5, tc = t & 31;
    const unsigned short* Abase = wvb + (size_t)tr * 128 * DIM;
    const unsigned short* Bbase = xb + (size_t)tc * 128 * DIM;

    f32x4 acc[2][4];
    #pragma unroll
    for (int m = 0; m < 2; ++m)
      #pragma unroll
      for (int n = 0; n < 4; ++n)
        acc[m][n] = (f32x4){0.f, 0.f, 0.f, 0.f};

    auto stage = [&](int buf, int kt) {
      const int k0 = kt << 6;
      #pragma unroll
      for (int i = 0; i < 2; ++i) {
        const int o = (i * 512 + tid) * 16;
        const int cs = (swz(o) >> 4) & 7;
        const unsigned short* ga = Abase + (size_t)(o >> 7) * DIM + k0 + cs * 8;
        const unsigned short* gb = Bbase + (size_t)(o >> 7) * DIM + k0 + cs * 8;
        __builtin_amdgcn_global_load_lds(
            (const __attribute__((address_space(1))) unsigned int*)ga,
            (__attribute__((address_space(3))) unsigned int*)((char*)(A0 + buf * 128 * 64) + o), 16, 0, 0);
        __builtin_amdgcn_global_load_lds(
            (const __attribute__((address_space(1))) unsigned int*)gb,
            (__attribute__((address_space(3))) unsigned int*)((char*)(B0 + buf * 128 * 64) + o), 16, 0, 0);
      }
    };

    stage(0, 0);
    int cur = 0;
    for (int kt = 0; kt < 16; ++kt) {
      if (kt + 1 < 16) { stage(cur ^ 1, kt + 1); wait_vm<4>(); }
      else wait_vm<0>();
      __builtin_amdgcn_s_barrier();

      bf16x8 af[2][2], bv[4][2];
      #pragma unroll
      for (int m = 0; m < 2; ++m)
        #pragma unroll
        for (int ks = 0; ks < 2; ++ks) {
          const int row = wr * 32 + m * 16 + l15;
          af[m][ks] = *reinterpret_cast<const bf16x8*>(
              (const char*)(A0 + cur * 128 * 64) + swz(row * 128 + kq * 16 + ks * 64));
        }
      #pragma unroll
      for (int n = 0; n < 4; ++n)
        #pragma unroll
        for (int ks = 0; ks < 2; ++ks) {
          const int row = wc * 64 + n * 16 + l15;
          bv[n][ks] = *reinterpret_cast<const bf16x8*>(
              (const char*)(B0 + cur * 128 * 64) + swz(row * 128 + kq * 16 + ks * 64));
        }
      #pragma unroll
      for (int m = 0; m < 2; ++m)
        #pragma unroll
        for (int n = 0; n < 4; ++n) {
          acc[m][n] = __builtin_amdgcn_mfma_f32_16x16x32_bf16(af[m][0], bv[n][0], acc[m][n], 0, 0, 0);
          acc[m][n] = __builtin_amdgcn_mfma_f32_16x16x32_bf16(af[m][1], bv[n][1], acc[m][n], 0, 0, 0);
        }
      __builtin_amdgcn_s_barrier();
      cur ^= 1;
    }

    const int rbase = tr * 128 + wr * 32 + kq * 4;
    const int cbase = tc * 128 + wc * 64 + l15;
    #pragma unroll
    for (int m = 0; m < 2; ++m)
      #pragma unroll
      for (int n = 0; n < 4; ++n)
        #pragma unroll
        for (int i = 0; i < 4; ++i)
          vt[(size_t)(rbase + m * 16 + i) * SEQ + cbase + n * 16] = f2bf(acc[m][n][i]);
    __builtin_amdgcn_s_barrier();
  }
}

// ---------------- PV GEMM (split-K, proven R5-R9) ----------------
__global__ void __launch_bounds__(256) pv_kernel(const unsigned short* __restrict__ A,
                                                 const unsigned short* __restrict__ B,
                                                 float* __restrict__ C,
                                                 float* __restrict__ P1, float* __restrict__ P2,
                                                 float* __restrict__ P3) {
  constexpr int BM = 64;
  constexpr int lda = SEQ, ldb = SEQ, ldc = DIM;
  int tc = blockIdx.x, tr = blockIdx.y;
  const int s = blockIdx.z;
  const int ltiles = tr + 1;
  int kt0 = s * 16;
  if (kt0 >= ltiles) return;
  const int nt = min(ltiles, kt0 + 16) - kt0;

  __shared__ __align__(16) unsigned short As[2][BM * 64];
  __shared__ __align__(16) unsigned short Bs[2][128 * 64];

  const int tid = threadIdx.x;
  const int lane = tid & 63;
  const int wid = tid >> 6;
  const int wr = wid >> 1, wc = wid & 1;
  const int l15 = lane & 15;
  const int kq = lane >> 4;

  f32x4 acc[2][4];
  #pragma unroll
  for (int m = 0; m < 2; ++m)
    #pragma unroll
    for (int n = 0; n < 4; ++n)
      acc[m][n] = (f32x4){0.f, 0.f, 0.f, 0.f};

  const unsigned short* Abase = A + (size_t)tr * BM * lda;
  const unsigned short* Bbase = B + (size_t)tc * 128 * ldb;

  auto stage = [&](int buf, int ktabs) {
    const int k0 = ktabs << 6;
    #pragma unroll
    for (int i = 0; i < 2; ++i) {
      const int o = (i * 256 + tid) * 16;
      const int cs = (swz(o) >> 4) & 7;
      const unsigned short* g = Abase + (size_t)(o >> 7) * lda + k0 + cs * 8;
      __builtin_amdgcn_global_load_lds(
          (const __attribute__((address_space(1))) unsigned int*)g,
          (__attribute__((address_space(3))) unsigned int*)((char*)&As[buf][0] + o), 16, 0, 0);
    }
    #pragma unroll
    for (int i = 0; i < 4; ++i) {
      const int o = (i * 256 + tid) * 16;
      const int cs = (swz(o) >> 4) & 7;
      const unsigned short* g = Bbase + (size_t)(o >> 7) * ldb + k0 + cs * 8;
      __builtin_amdgcn_global_load_lds(
          (const __attribute__((address_space(1))) unsigned int*)g,
          (__attribute__((address_space(3))) unsigned int*)((char*)&Bs[buf][0] + o), 16, 0, 0);
    }
  };

  stage(0, kt0);
  int cur = 0;
  for (int kt = 0; kt < nt; ++kt) {
    if (kt + 1 < nt) { stage(cur ^ 1, kt0 + kt + 1); wait_vm<6>(); }
    else wait_vm<0>();
    __builtin_amdgcn_s_barrier();

    bf16x8 af[2][2], bv[4][2];
    #pragma unroll
    for (int m = 0; m < 2; ++m)
      #pragma unroll
      for (int ks = 0; ks < 2; ++ks) {
        const int row = wr * 32 + m * 16 + l15;
        af[m][ks] = *reinterpret_cast<const bf16x8*>(
            (const char*)&As[cur][0] + swz(row * 128 + kq * 16 + ks * 64));
      }
    #pragma unroll
    for (int n = 0; n < 4; ++n)
      #pragma unroll
      for (int ks = 0; ks < 2; ++ks) {
        const int row = wc * 64 + n * 16 + l15;
        bv[n][ks] = *reinterpret_cast<const bf16x8*>(
            (const char*)&Bs[cur][0] + swz(row * 128 + kq * 16 + ks * 64));
      }
    #pragma unroll
    for (int m = 0; m < 2; ++m)
      #pragma unroll
      for (int n = 0; n < 4; ++n) {
        acc[m][n] = __builtin_amdgcn_mfma_f32_16x16x32_bf16(af[m][0], bv[n][0], acc[m][n], 0, 0, 0);
        acc[m][n] = __builtin_amdgcn_mfma_f32_16x16x32_bf16(af[m][1], bv[n][1], acc[m][n], 0, 0, 0);
      }
    __builtin_amdgcn_s_barrier();
    cur ^= 1;
  }

  float* fdst = C;
  int rowoff = 0;
  if (s == 1) { fdst = P1; rowoff = 1024; }
  else if (s == 2) { fdst = P2; rowoff = 2048; }
  else if (s == 3) { fdst = P3; rowoff = 3072; }
  const int rbase = tr * BM + wr * 32 + kq * 4;
  const int cbase = tc * 128 + wc * 64 + l15;
  #pragma unroll
  for (int m = 0; m < 2; ++m)
    #pragma unroll
    for (int n = 0; n < 4; ++n)
      #pragma unroll
      for (int i = 0; i < 4; ++i)
        fdst[(size_t)(rbase + m * 16 + i - rowoff) * ldc + cbase + n * 16] = acc[m][n][i];
}

// ---------------- split-K reduction ----------------
__global__ void __launch_bounds__(256) reduce_kernel(float* __restrict__ out,
                                                     const float* __restrict__ p1,
                                                     const float* __restrict__ p2,
                                                     const float* __restrict__ p3) {
  const int b = blockIdx.x;
  const size_t e = ((size_t)b * 1024) + threadIdx.x * 4;
  f32x4 acc = *reinterpret_cast<f32x4*>(out + (size_t)1024 * 1024 + e);
  acc += *reinterpret_cast<const f32x4*>(p1 + e);
  if (b >= 1024) acc += *reinterpret_cast<const f32x4*>(p2 + e - (size_t)1024 * 1024);
  if (b >= 2048) acc += *reinterpret_cast<const f32x4*>(p3 + e - (size_t)2048 * 1024);
  *reinterpret_cast<f32x4*>(out + (size_t)1024 * 1024 + e) = acc;
}

// ---------------- in-place causal row softmax ----------------
__global__ void __launch_bounds__(256) softmax_causal(unsigned short* __restrict__ S) {
  const int row = blockIdx.x;
  const int limit = ((row >> 6) + 1) << 6;
  unsigned short* Srow = S + (size_t)row * SEQ;
  const int tid = threadIdx.x;
  const int lane = tid & 63, wid = tid >> 6;

  float vals[16];
  bool act[2];
  #pragma unroll
  for (int i = 0; i < 2; ++i) {
    const int j0 = (tid + i * 256) * 8;
    act[i] = j0 < limit;
    if (act[i]) {
      const uint4 w = *reinterpret_cast<const uint4*>(Srow + j0);
      const unsigned int wb[4] = {w.x, w.y, w.z, w.w};
      #pragma unroll
      for (int e = 0; e < 4; ++e) {
        vals[i * 8 + 2 * e]     = __uint_as_float(wb[e] << 16);
        vals[i * 8 + 2 * e + 1] = __uint_as_float(wb[e] & 0xFFFF0000u);
      }
    } else {
      #pragma unroll
      for (int e = 0; e < 8; ++e) vals[i * 8 + e] = -1e30f;
    }
  }

  float m = -1e30f;
  #pragma unroll
  for (int i = 0; i < 2; ++i)
    #pragma unroll
    for (int e = 0; e < 8; ++e) {
      int j = (tid + i * 256) * 8 + e;
      if (j <= row) m = fmaxf(m, vals[i * 8 + e]);
    }
  #pragma unroll
  for (int off = 32; off > 0; off >>= 1) m = fmaxf(m, __shfl_xor(m, off));
  __shared__ float redm[4], reds[4];
  if (lane == 0) redm[wid] = m;
  __syncthreads();
  m = fmaxf(fmaxf(redm[0], redm[1]), fmaxf(redm[2], redm[3]));

  float s = 0.f;
  float ev[16];
  #pragma unroll
  for (int i = 0; i < 2; ++i)
    #pragma unroll
    for (int e = 0; e < 8; ++e) {
      int j = (tid + i * 256) * 8 + e;
      float ex = (j <= row) ? __expf(vals[i * 8 + e] - m) : 0.f;
      ev[i * 8 + e] = ex;
      s += ex;
    }
  #pragma unroll
  for (int off = 32; off > 0; off >>= 1) s += __shfl_xor(s, off);
  if (lane == 0) reds[wid] = s;
  __syncthreads();
  s = reds[0] + reds[1] + reds[2] + reds[3];
  const float inv = 1.f / s;

  #pragma unroll
  for (int i = 0; i < 2; ++i) {
    if (!act[i]) continue;
    u16x8 o;
    #pragma unroll
    for (int e = 0; e < 8; ++e) o[e] = f2bf(ev[i * 8 + e] * inv);
    *reinterpret_cast<u16x8*>(Srow + (tid + i * 256) * 8) = o;
  }
}

extern "C" void kernel_launch(void* const* d_in, const int* in_sizes, int n_in,
                              void* d_out, int out_size, void* d_ws, size_t ws_size,
                              hipStream_t stream) {
  const float* x  = (const float*)d_in[0];
  const float* Wq = (const float*)d_in[1];
  const float* Wk = (const float*)d_in[2];
  const float* Wv = (const float*)d_in[3];
  float* out = (float*)d_out;

  char* ws = (char*)d_ws;
  const size_t MB = 1u << 20;
  unsigned short* xb   = (unsigned short*)(ws + 0 * MB);   // 8 MB
  unsigned short* wqk  = (unsigned short*)(ws + 8 * MB);   // 4 MB
  unsigned short* wvb  = (unsigned short*)(ws + 12 * MB);  // 2 MB
  unsigned short* qkb  = (unsigned short*)(ws + 14 * MB);  // 16 MB Q|K [4096][2048]
  unsigned short* vt   = (unsigned short*)(ws + 30 * MB);  // 8 MB  V^T [1024][4096]
  unsigned short* S    = (unsigned short*)(ws + 38 * MB);  // 32 MB (-> P in place)
  float* p1 = (float*)(ws + 0 * MB);    // 12 MB (reuse after qkt_vt)
  float* p2 = (float*)(ws + 12 * MB);   // 8 MB
  float* p3 = (float*)(ws + 20 * MB);   // 4 MB

  cvt_all<<<3584, 256, 0, stream>>>(x, Wq, Wk, Wv, xb, wqk, wvb);

  // Q|K projection only (512 blocks, exactly 2/CU, one round)
  proj_qk<<<512, 256, 0, stream>>>(xb, wqk, qkb);

  // causal QK^T (136 blocks, 16x16 body) + V^T projection (120 blocks)
  qkt_vt<<<256, 512, 0, stream>>>(qkb, qkb + 1024, S, wvb, xb, vt);

  softmax_causal<<<SEQ, 256, 0, stream>>>(S);

  pv_kernel<<<dim3(DIM / 128, SEQ / 64, 4), 256, 0, stream>>>(S, vt, out, p1, p2, p3);
  reduce_kernel<<<3072, 256, 0, stream>>>(out, p1, p2, p3);
}